// Round 1
// baseline (16335.176 us; speedup 1.0000x reference)
//
#include <hip/hip_runtime.h>

#define Tn 512
#define Bn 64
#define Nn 1024
#define Hn 512

// ---------------------------------------------------------------------------
// k0: SP[b][j] = sum_i s[b][i] * W1[j][i]  + b1[j]    (first half of W1 rows)
// ---------------------------------------------------------------------------
__global__ __launch_bounds__(256) void k0_sproj(const float* __restrict__ s,
    const float* __restrict__ W1, const float* __restrict__ b1,
    float* __restrict__ SP) {
  const int b = blockIdx.x;
  const int tid = threadIdx.x;
  __shared__ float sl[Nn];
  for (int i = tid; i < Nn; i += 256) sl[i] = s[(size_t)b * Nn + i];
  __syncthreads();
#pragma unroll
  for (int qq = 0; qq < 4; ++qq) {
    const int j = qq * 256 + tid;
    const float* w = W1 + (size_t)j * (2 * Nn);
    float acc = 0.f;
    for (int i = 0; i < Nn; i += 4) {
      const float4 wv = *(const float4*)(w + i);
      acc += sl[i] * wv.x + sl[i + 1] * wv.y + sl[i + 2] * wv.z + sl[i + 3] * wv.w;
    }
    SP[(size_t)b * Nn + j] = acc + b1[j];
  }
}

// ---------------------------------------------------------------------------
// k1: XW[m][j] = sum_k X[m][k] * Wcat[j][k] + bias[j]
//   m = t*64+b (32768), j<512 -> Wih_f row j (+bih_f), j>=512 -> Wih_b (+bih_b)
//   BM=128 BN=256 BK=8, 256 threads, 8x16 micro-tile
// ---------------------------------------------------------------------------
__global__ __launch_bounds__(256) void k1_gemm(const float* __restrict__ X,
    const float* __restrict__ Wf, const float* __restrict__ Wb,
    const float* __restrict__ bif, const float* __restrict__ bib,
    float* __restrict__ XW) {
  __shared__ __align__(16) float As[8 * 128];
  __shared__ __align__(16) float Bs[8 * 256];
  const int tid = threadIdx.x;
  const int m0 = blockIdx.x * 128;
  const int n0 = blockIdx.y * 256;
  const int mt = tid & 15;
  const int nt = tid >> 4;
  float acc[8][16];
#pragma unroll
  for (int i = 0; i < 8; ++i)
#pragma unroll
    for (int j = 0; j < 16; ++j) acc[i][j] = 0.f;
  const int jg = n0 + tid;
  const float* brow = (jg < 512) ? (Wf + (size_t)jg * Nn) : (Wb + (size_t)(jg - 512) * Nn);
  const int ai = tid >> 1;
  const int ak = (tid & 1) * 4;
  const float* arow = X + (size_t)(m0 + ai) * Nn + ak;
  for (int kt = 0; kt < 128; ++kt) {
    const int k0 = kt * 8;
    const float4 av = *(const float4*)(arow + k0);
    const float4 bv0 = *(const float4*)(brow + k0);
    const float4 bv1 = *(const float4*)(brow + k0 + 4);
    __syncthreads();
    As[(ak + 0) * 128 + ai] = av.x;
    As[(ak + 1) * 128 + ai] = av.y;
    As[(ak + 2) * 128 + ai] = av.z;
    As[(ak + 3) * 128 + ai] = av.w;
    Bs[0 * 256 + tid] = bv0.x;
    Bs[1 * 256 + tid] = bv0.y;
    Bs[2 * 256 + tid] = bv0.z;
    Bs[3 * 256 + tid] = bv0.w;
    Bs[4 * 256 + tid] = bv1.x;
    Bs[5 * 256 + tid] = bv1.y;
    Bs[6 * 256 + tid] = bv1.z;
    Bs[7 * 256 + tid] = bv1.w;
    __syncthreads();
#pragma unroll
    for (int k = 0; k < 8; ++k) {
      float a[8], bq[16];
      *(float4*)&a[0] = *(const float4*)&As[k * 128 + mt * 8];
      *(float4*)&a[4] = *(const float4*)&As[k * 128 + mt * 8 + 4];
      *(float4*)&bq[0] = *(const float4*)&Bs[k * 256 + nt * 16];
      *(float4*)&bq[4] = *(const float4*)&Bs[k * 256 + nt * 16 + 4];
      *(float4*)&bq[8] = *(const float4*)&Bs[k * 256 + nt * 16 + 8];
      *(float4*)&bq[12] = *(const float4*)&Bs[k * 256 + nt * 16 + 12];
#pragma unroll
      for (int mi = 0; mi < 8; ++mi)
#pragma unroll
        for (int ni = 0; ni < 16; ++ni) acc[mi][ni] += a[mi] * bq[ni];
    }
  }
  float bias[16];
#pragma unroll
  for (int ni = 0; ni < 16; ++ni) {
    const int jc = n0 + nt * 16 + ni;
    bias[ni] = (jc < 512) ? bif[jc] : bib[jc - 512];
  }
#pragma unroll
  for (int mi = 0; mi < 8; ++mi) {
    float* orow = XW + (size_t)(m0 + mt * 8 + mi) * Nn + n0 + nt * 16;
#pragma unroll
    for (int c = 0; c < 4; ++c) {
      float4 v;
      v.x = acc[mi][c * 4 + 0] + bias[c * 4 + 0];
      v.y = acc[mi][c * 4 + 1] + bias[c * 4 + 1];
      v.z = acc[mi][c * 4 + 2] + bias[c * 4 + 2];
      v.w = acc[mi][c * 4 + 3] + bias[c * 4 + 3];
      *(float4*)(orow + c * 4) = v;
    }
  }
}

// ---------------------------------------------------------------------------
// k2: bidirectional RNN scan.  256 WGs = 2 dir x 8 bgroup x 16 rgroup.
//   Whh slice (32 rows x 512 k) transposed in LDS; h_prev via uniform loads;
//   cross-WG per-step sync via t-indexed flag counters.
// ---------------------------------------------------------------------------
__global__ __launch_bounds__(256) void k2_scan(const float* __restrict__ XW,
    const float* __restrict__ Whh_f, const float* __restrict__ Whh_b,
    const float* __restrict__ bhh_f, const float* __restrict__ bhh_b,
    float* __restrict__ Hm, int* __restrict__ FL) {
  const int wg = blockIdx.x;
  const int dir = wg & 1;
  const int bg = (wg >> 1) & 7;
  const int rg = wg >> 4;  // 0..15
  const int tid = threadIdx.x;
  const int r = tid & 31;   // row within slice
  const int q = tid >> 5;   // k-slice 0..7 (64 k each)
  __shared__ float Wt[512 * 32];     // [k][r]  64KB
  __shared__ float red[8 * 8 * 32];  // [q][bb][r] 8KB
  const float* Whh = dir ? Whh_b : Whh_f;
  const float* bhh = dir ? bhh_b : bhh_f;
  for (int idx = tid; idx < 32 * 128; idx += 256) {
    const int rl = idx & 31;
    const int k4 = idx >> 5;
    const float4 v = *(const float4*)(Whh + (size_t)(rg * 32 + rl) * Hn + k4 * 4);
    Wt[(k4 * 4 + 0) * 32 + rl] = v.x;
    Wt[(k4 * 4 + 1) * 32 + rl] = v.y;
    Wt[(k4 * 4 + 2) * 32 + rl] = v.z;
    Wt[(k4 * 4 + 3) * 32 + rl] = v.w;
  }
  const float bhh_r = bhh[rg * 32 + r];
  const int bb2 = tid >> 5;            // epilogue: 8 bb x 32 r
  const int bglob2 = bg * 8 + bb2;
  const int rglob = rg * 32 + r;
  const int coloff = dir * 512;
  const int k_lo = q * 64;
  for (int t = 0; t < Tn; ++t) {
    if (t > 0 && tid == 0) {
      int* fp = FL + ((dir << 9) + (t - 1)) * 8 + bg;
      while (__hip_atomic_load(fp, __ATOMIC_ACQUIRE, __HIP_MEMORY_SCOPE_AGENT) < 16) {
        __builtin_amdgcn_s_sleep(2);
      }
    }
    __syncthreads();
    if (t > 0) {
      const int hprow = dir ? (Tn - t) : (t - 1);
      const float* hp = Hm + (size_t)hprow * (Bn * Nn) + (size_t)(bg * 8) * Nn + coloff;
      float acc[8] = {0.f, 0.f, 0.f, 0.f, 0.f, 0.f, 0.f, 0.f};
      for (int k0 = k_lo; k0 < k_lo + 64; k0 += 4) {
        const float w0 = Wt[(k0 + 0) * 32 + r];
        const float w1 = Wt[(k0 + 1) * 32 + r];
        const float w2_ = Wt[(k0 + 2) * 32 + r];
        const float w3 = Wt[(k0 + 3) * 32 + r];
#pragma unroll
        for (int bb = 0; bb < 8; ++bb) {
          const float4 hv = *(const float4*)(hp + (size_t)bb * Nn + k0);
          acc[bb] += hv.x * w0 + hv.y * w1 + hv.z * w2_ + hv.w * w3;
        }
      }
#pragma unroll
      for (int bb = 0; bb < 8; ++bb) red[q * 256 + bb * 32 + r] = acc[bb];
    }
    __syncthreads();
    float ssum = 0.f;
    if (t > 0) {
#pragma unroll
      for (int qq = 0; qq < 8; ++qq) ssum += red[qq * 256 + bb2 * 32 + r];
    }
    const size_t xwrow = dir ? ((size_t)(Tn - 1 - t) * Bn + bglob2)
                             : ((size_t)t * Bn + bglob2);
    const float pre = ssum + XW[xwrow * Nn + coloff + rglob] + bhh_r;
    const float hv = tanhf(pre);
    const int hrow = dir ? (Tn - 1 - t) : t;
    Hm[(size_t)hrow * (Bn * Nn) + (size_t)bglob2 * Nn + coloff + rglob] = hv;
    __threadfence();
    __syncthreads();
    if (tid == 0) atomicAdd(FL + ((dir << 9) + t) * 8 + bg, 1);
  }
}

// ---------------------------------------------------------------------------
// k3: EP[tb] += sum_j W2[j] * tanh( sum_k H[tb][k]*W1[j][N+k] + SP[b][j] )
//   same GEMM skeleton as k1, fused epilogue (u never materialized)
// ---------------------------------------------------------------------------
__global__ __launch_bounds__(256) void k3_attn(const float* __restrict__ Hm,
    const float* __restrict__ W1, const float* __restrict__ SP,
    const float* __restrict__ W2, float* __restrict__ EP) {
  __shared__ __align__(16) float As[8 * 128];
  __shared__ __align__(16) float Bs[8 * 256];
  __shared__ float esc[128 * 16];
  const int tid = threadIdx.x;
  const int m0 = blockIdx.x * 128;
  const int n0 = blockIdx.y * 256;
  const int mt = tid & 15;
  const int nt = tid >> 4;
  float acc[8][16];
#pragma unroll
  for (int i = 0; i < 8; ++i)
#pragma unroll
    for (int j = 0; j < 16; ++j) acc[i][j] = 0.f;
  const float* brow = W1 + (size_t)(n0 + tid) * (2 * Nn) + Nn;
  const int ai = tid >> 1;
  const int ak = (tid & 1) * 4;
  const float* arow = Hm + (size_t)(m0 + ai) * Nn + ak;
  for (int kt = 0; kt < 128; ++kt) {
    const int k0 = kt * 8;
    const float4 av = *(const float4*)(arow + k0);
    const float4 bv0 = *(const float4*)(brow + k0);
    const float4 bv1 = *(const float4*)(brow + k0 + 4);
    __syncthreads();
    As[(ak + 0) * 128 + ai] = av.x;
    As[(ak + 1) * 128 + ai] = av.y;
    As[(ak + 2) * 128 + ai] = av.z;
    As[(ak + 3) * 128 + ai] = av.w;
    Bs[0 * 256 + tid] = bv0.x;
    Bs[1 * 256 + tid] = bv0.y;
    Bs[2 * 256 + tid] = bv0.z;
    Bs[3 * 256 + tid] = bv0.w;
    Bs[4 * 256 + tid] = bv1.x;
    Bs[5 * 256 + tid] = bv1.y;
    Bs[6 * 256 + tid] = bv1.z;
    Bs[7 * 256 + tid] = bv1.w;
    __syncthreads();
#pragma unroll
    for (int k = 0; k < 8; ++k) {
      float a[8], bq[16];
      *(float4*)&a[0] = *(const float4*)&As[k * 128 + mt * 8];
      *(float4*)&a[4] = *(const float4*)&As[k * 128 + mt * 8 + 4];
      *(float4*)&bq[0] = *(const float4*)&Bs[k * 256 + nt * 16];
      *(float4*)&bq[4] = *(const float4*)&Bs[k * 256 + nt * 16 + 4];
      *(float4*)&bq[8] = *(const float4*)&Bs[k * 256 + nt * 16 + 8];
      *(float4*)&bq[12] = *(const float4*)&Bs[k * 256 + nt * 16 + 12];
#pragma unroll
      for (int mi = 0; mi < 8; ++mi)
#pragma unroll
        for (int ni = 0; ni < 16; ++ni) acc[mi][ni] += a[mi] * bq[ni];
    }
  }
  float w2v[16];
  *(float4*)&w2v[0] = *(const float4*)(W2 + n0 + nt * 16);
  *(float4*)&w2v[4] = *(const float4*)(W2 + n0 + nt * 16 + 4);
  *(float4*)&w2v[8] = *(const float4*)(W2 + n0 + nt * 16 + 8);
  *(float4*)&w2v[12] = *(const float4*)(W2 + n0 + nt * 16 + 12);
#pragma unroll
  for (int mi = 0; mi < 8; ++mi) {
    const int row = m0 + mt * 8 + mi;
    const int b = row & 63;
    const float* sp = SP + (size_t)b * Nn + n0 + nt * 16;
    float rp = 0.f;
#pragma unroll
    for (int ni = 0; ni < 16; ++ni) {
      const float u = tanhf(acc[mi][ni] + sp[ni]);
      rp += u * w2v[ni];
    }
    esc[(mt * 8 + mi) * 16 + nt] = rp;
  }
  __syncthreads();
  if (tid < 128) {
    float sum = 0.f;
#pragma unroll
    for (int qq = 0; qq < 16; ++qq) sum += esc[tid * 16 + qq];
    atomicAdd(EP + m0 + tid, sum);
  }
}

// ---------------------------------------------------------------------------
// k4: e = tanh(EP + b2); softmax over t (per b)
// ---------------------------------------------------------------------------
__global__ __launch_bounds__(256) void k4_softmax(const float* __restrict__ EP,
    const float* __restrict__ b2, float* __restrict__ AA) {
  const int b = blockIdx.x;
  const int tid = threadIdx.x;
  __shared__ float rbuf[256];
  const float b2v = b2[0];
  const float v0 = tanhf(EP[(size_t)tid * Bn + b] + b2v);
  const float v1 = tanhf(EP[(size_t)(tid + 256) * Bn + b] + b2v);
  rbuf[tid] = fmaxf(v0, v1);
  __syncthreads();
  for (int off = 128; off > 0; off >>= 1) {
    if (tid < off) rbuf[tid] = fmaxf(rbuf[tid], rbuf[tid + off]);
    __syncthreads();
  }
  const float M = rbuf[0];
  __syncthreads();
  const float e0 = expf(v0 - M);
  const float e1 = expf(v1 - M);
  rbuf[tid] = e0 + e1;
  __syncthreads();
  for (int off = 128; off > 0; off >>= 1) {
    if (tid < off) rbuf[tid] = rbuf[tid] + rbuf[tid + off];
    __syncthreads();
  }
  const float S = rbuf[0];
  AA[(size_t)tid * Bn + b] = e0 / S;
  AA[(size_t)(tid + 256) * Bn + b] = e1 / S;
}

// ---------------------------------------------------------------------------
// k5: out[b][n] = sum_t AA[t][b] * H[t][b][n]
// ---------------------------------------------------------------------------
__global__ __launch_bounds__(256) void k5_out(const float* __restrict__ AA,
    const float* __restrict__ Hm, float* __restrict__ out) {
  const int b = blockIdx.x;
  const int n = blockIdx.y * 256 + threadIdx.x;
  float o = 0.f;
#pragma unroll 8
  for (int t = 0; t < Tn; ++t)
    o += AA[(size_t)t * Bn + b] * Hm[(size_t)t * (Bn * Nn) + (size_t)b * Nn + n];
  out[(size_t)b * Nn + n] = o;
}

// ---------------------------------------------------------------------------
extern "C" void kernel_launch(void* const* d_in, const int* in_sizes, int n_in,
                              void* d_out, int out_size, void* d_ws, size_t ws_size,
                              hipStream_t stream) {
  const float* s     = (const float*)d_in[0];
  const float* x     = (const float*)d_in[1];
  const float* Wih_f = (const float*)d_in[2];
  const float* Whh_f = (const float*)d_in[3];
  const float* bih_f = (const float*)d_in[4];
  const float* bhh_f = (const float*)d_in[5];
  const float* Wih_b = (const float*)d_in[6];
  const float* Whh_b = (const float*)d_in[7];
  const float* bih_b = (const float*)d_in[8];
  const float* bhh_b = (const float*)d_in[9];
  const float* W1    = (const float*)d_in[10];
  const float* b1    = (const float*)d_in[11];
  const float* W2    = (const float*)d_in[12];
  const float* b2    = (const float*)d_in[13];
  float* out = (float*)d_out;

  float* XW = (float*)d_ws;                 // 33554432 f32 (134MB)
  float* Hm = XW + 33554432ULL;             // 33554432 f32 (134MB)
  float* SP = Hm + 33554432ULL;             // 65536 f32
  float* EP = SP + 65536ULL;                // 32768 f32
  float* AA = EP + 32768ULL;                // 32768 f32
  int* FL   = (int*)(AA + 32768ULL);        // 2*512*8 = 8192 ints
  const size_t need = ((size_t)(33554432ULL * 2 + 65536 + 32768 + 32768)) * 4 + 8192 * 4;
  if (ws_size < need) return;  // workspace too small: fail visibly

  hipMemsetAsync(EP, 0, 32768 * sizeof(float), stream);
  hipMemsetAsync(FL, 0, 8192 * sizeof(int), stream);

  k0_sproj<<<dim3(64), 256, 0, stream>>>(s, W1, b1, SP);
  k1_gemm<<<dim3(256, 4), 256, 0, stream>>>(x, Wih_f, Wih_b, bih_f, bih_b, XW);
  k2_scan<<<dim3(256), 256, 0, stream>>>(XW, Whh_f, Whh_b, bhh_f, bhh_b, Hm, FL);
  k3_attn<<<dim3(256, 4), 256, 0, stream>>>(Hm, W1, SP, W2, EP);
  k4_softmax<<<dim3(64), 256, 0, stream>>>(EP, b2, AA);
  k5_out<<<dim3(64, 4), 256, 0, stream>>>(AA, Hm, out);
}

// Round 2
// 7999.438 us; speedup vs baseline: 2.0420x; 2.0420x over previous
//
#include <hip/hip_runtime.h>

#define Tn 512
#define Bn 64
#define Nn 1024
#define Hn 512

// ---------------------------------------------------------------------------
// k0: SP[b][j] = sum_i s[b][i] * W1[j][i]  + b1[j]    (first half of W1 rows)
// ---------------------------------------------------------------------------
__global__ __launch_bounds__(256) void k0_sproj(const float* __restrict__ s,
    const float* __restrict__ W1, const float* __restrict__ b1,
    float* __restrict__ SP) {
  const int b = blockIdx.x;
  const int tid = threadIdx.x;
  __shared__ float sl[Nn];
  for (int i = tid; i < Nn; i += 256) sl[i] = s[(size_t)b * Nn + i];
  __syncthreads();
#pragma unroll
  for (int qq = 0; qq < 4; ++qq) {
    const int j = qq * 256 + tid;
    const float* w = W1 + (size_t)j * (2 * Nn);
    float acc = 0.f;
    for (int i = 0; i < Nn; i += 4) {
      const float4 wv = *(const float4*)(w + i);
      acc += sl[i] * wv.x + sl[i + 1] * wv.y + sl[i + 2] * wv.z + sl[i + 3] * wv.w;
    }
    SP[(size_t)b * Nn + j] = acc + b1[j];
  }
}

// ---------------------------------------------------------------------------
// k1: XW[m][j] = sum_k X[m][k] * Wcat[j][k] + bias[j]
//   m = t*64+b (32768), j<512 -> Wih_f row j (+bih_f), j>=512 -> Wih_b (+bih_b)
//   BM=128 BN=256 BK=8, 256 threads, 8x16 micro-tile
// ---------------------------------------------------------------------------
__global__ __launch_bounds__(256) void k1_gemm(const float* __restrict__ X,
    const float* __restrict__ Wf, const float* __restrict__ Wb,
    const float* __restrict__ bif, const float* __restrict__ bib,
    float* __restrict__ XW) {
  __shared__ __align__(16) float As[8 * 128];
  __shared__ __align__(16) float Bs[8 * 256];
  const int tid = threadIdx.x;
  const int m0 = blockIdx.x * 128;
  const int n0 = blockIdx.y * 256;
  const int mt = tid & 15;
  const int nt = tid >> 4;
  float acc[8][16];
#pragma unroll
  for (int i = 0; i < 8; ++i)
#pragma unroll
    for (int j = 0; j < 16; ++j) acc[i][j] = 0.f;
  const int jg = n0 + tid;
  const float* brow = (jg < 512) ? (Wf + (size_t)jg * Nn) : (Wb + (size_t)(jg - 512) * Nn);
  const int ai = tid >> 1;
  const int ak = (tid & 1) * 4;
  const float* arow = X + (size_t)(m0 + ai) * Nn + ak;
  for (int kt = 0; kt < 128; ++kt) {
    const int k0 = kt * 8;
    const float4 av = *(const float4*)(arow + k0);
    const float4 bv0 = *(const float4*)(brow + k0);
    const float4 bv1 = *(const float4*)(brow + k0 + 4);
    __syncthreads();
    As[(ak + 0) * 128 + ai] = av.x;
    As[(ak + 1) * 128 + ai] = av.y;
    As[(ak + 2) * 128 + ai] = av.z;
    As[(ak + 3) * 128 + ai] = av.w;
    Bs[0 * 256 + tid] = bv0.x;
    Bs[1 * 256 + tid] = bv0.y;
    Bs[2 * 256 + tid] = bv0.z;
    Bs[3 * 256 + tid] = bv0.w;
    Bs[4 * 256 + tid] = bv1.x;
    Bs[5 * 256 + tid] = bv1.y;
    Bs[6 * 256 + tid] = bv1.z;
    Bs[7 * 256 + tid] = bv1.w;
    __syncthreads();
#pragma unroll
    for (int k = 0; k < 8; ++k) {
      float a[8], bq[16];
      *(float4*)&a[0] = *(const float4*)&As[k * 128 + mt * 8];
      *(float4*)&a[4] = *(const float4*)&As[k * 128 + mt * 8 + 4];
      *(float4*)&bq[0] = *(const float4*)&Bs[k * 256 + nt * 16];
      *(float4*)&bq[4] = *(const float4*)&Bs[k * 256 + nt * 16 + 4];
      *(float4*)&bq[8] = *(const float4*)&Bs[k * 256 + nt * 16 + 8];
      *(float4*)&bq[12] = *(const float4*)&Bs[k * 256 + nt * 16 + 12];
#pragma unroll
      for (int mi = 0; mi < 8; ++mi)
#pragma unroll
        for (int ni = 0; ni < 16; ++ni) acc[mi][ni] += a[mi] * bq[ni];
    }
  }
  float bias[16];
#pragma unroll
  for (int ni = 0; ni < 16; ++ni) {
    const int jc = n0 + nt * 16 + ni;
    bias[ni] = (jc < 512) ? bif[jc] : bib[jc - 512];
  }
#pragma unroll
  for (int mi = 0; mi < 8; ++mi) {
    float* orow = XW + (size_t)(m0 + mt * 8 + mi) * Nn + n0 + nt * 16;
#pragma unroll
    for (int c = 0; c < 4; ++c) {
      float4 v;
      v.x = acc[mi][c * 4 + 0] + bias[c * 4 + 0];
      v.y = acc[mi][c * 4 + 1] + bias[c * 4 + 1];
      v.z = acc[mi][c * 4 + 2] + bias[c * 4 + 2];
      v.w = acc[mi][c * 4 + 3] + bias[c * 4 + 3];
      *(float4*)(orow + c * 4) = v;
    }
  }
}

// ---------------------------------------------------------------------------
// k2: bidirectional RNN scan.  256 WGs = 2 dir x 8 bgroup x 16 rgroup.
//   Whh slice (32 rows x 512 k) transposed in LDS; cross-WG per-step sync via
//   per-(dir,t,bg,rg) write-once flags:
//     producer: sc1 write-through h stores -> vmcnt(0) -> barrier -> sc1 flag=1
//     consumer: 16-lane relaxed coalesced poll -> ONE acquire fence (buffer_inv)
//   (previous round: acquire-per-poll + __threadfence = buffer_inv/wbl2 storm,
//    27.8us/step; this protocol does exactly one inv per step per WG)
// ---------------------------------------------------------------------------
__global__ __launch_bounds__(256) void k2_scan(const float* __restrict__ XW,
    const float* __restrict__ Whh_f, const float* __restrict__ Whh_b,
    const float* __restrict__ bhh_f, const float* __restrict__ bhh_b,
    float* __restrict__ Hm, int* __restrict__ FL) {
  const int wg = blockIdx.x;
  const int dir = wg & 1;
  const int bg = (wg >> 1) & 7;
  const int rg = wg >> 4;  // 0..15
  const int tid = threadIdx.x;
  const int r = tid & 31;   // row within slice
  const int q = tid >> 5;   // k-slice 0..7 (64 k each)
  __shared__ float Wt[512 * 32];     // [k][r]  64KB
  __shared__ float red[8 * 8 * 32];  // [q][bb][r] 8KB
  const float* Whh = dir ? Whh_b : Whh_f;
  const float* bhh = dir ? bhh_b : bhh_f;
  for (int idx = tid; idx < 32 * 128; idx += 256) {
    const int rl = idx & 31;
    const int k4 = idx >> 5;
    const float4 v = *(const float4*)(Whh + (size_t)(rg * 32 + rl) * Hn + k4 * 4);
    Wt[(k4 * 4 + 0) * 32 + rl] = v.x;
    Wt[(k4 * 4 + 1) * 32 + rl] = v.y;
    Wt[(k4 * 4 + 2) * 32 + rl] = v.z;
    Wt[(k4 * 4 + 3) * 32 + rl] = v.w;
  }
  const float bhh_r = bhh[rg * 32 + r];
  const int bb2 = tid >> 5;            // epilogue: 8 bb x 32 r
  const int bglob2 = bg * 8 + bb2;
  const int rglob = rg * 32 + r;
  const int coloff = dir * 512;
  const int k_lo = q * 64;
  for (int t = 0; t < Tn; ++t) {
    // issue this step's XW load before the flag wait (independent of h[t-1])
    const size_t xwrow = dir ? ((size_t)(Tn - 1 - t) * Bn + bglob2)
                             : ((size_t)t * Bn + bglob2);
    const float xwv = XW[xwrow * Nn + coloff + rglob];

    if (t > 0) {
      if (tid < 64) {  // wave 0: 16 flags polled in one coalesced load
        int* fp = FL + (size_t)(((dir << 9) | (t - 1)) * 8 + bg) * 16;
        while (true) {
          const int v = __hip_atomic_load(fp + (tid & 15), __ATOMIC_RELAXED,
                                          __HIP_MEMORY_SCOPE_AGENT);
          if (__all(v != 0)) break;
          __builtin_amdgcn_s_sleep(1);
        }
      }
      __syncthreads();
      __builtin_amdgcn_fence(__ATOMIC_ACQUIRE, "agent");  // one buffer_inv/step
      const int hprow = dir ? (Tn - t) : (t - 1);
      const float* hp = Hm + (size_t)hprow * (Bn * Nn) + (size_t)(bg * 8) * Nn + coloff;
      float acc[8] = {0.f, 0.f, 0.f, 0.f, 0.f, 0.f, 0.f, 0.f};
      for (int k0 = k_lo; k0 < k_lo + 64; k0 += 4) {
        const float w0 = Wt[(k0 + 0) * 32 + r];
        const float w1 = Wt[(k0 + 1) * 32 + r];
        const float w2_ = Wt[(k0 + 2) * 32 + r];
        const float w3 = Wt[(k0 + 3) * 32 + r];
#pragma unroll
        for (int bb = 0; bb < 8; ++bb) {
          const float4 hv = *(const float4*)(hp + (size_t)bb * Nn + k0);
          acc[bb] += hv.x * w0 + hv.y * w1 + hv.z * w2_ + hv.w * w3;
        }
      }
#pragma unroll
      for (int bb = 0; bb < 8; ++bb) red[q * 256 + bb * 32 + r] = acc[bb];
    }
    __syncthreads();
    float ssum = 0.f;
    if (t > 0) {
#pragma unroll
      for (int qq = 0; qq < 8; ++qq) ssum += red[qq * 256 + bb2 * 32 + r];
    }
    const float pre = ssum + xwv + bhh_r;
    const float hv = tanhf(pre);
    const int hrow = dir ? (Tn - 1 - t) : t;
    // write-through (sc1) store: visible at LLC once vmcnt retires; no dirty L2
    __hip_atomic_store(
        &Hm[(size_t)hrow * (Bn * Nn) + (size_t)bglob2 * Nn + coloff + rglob], hv,
        __ATOMIC_RELAXED, __HIP_MEMORY_SCOPE_AGENT);
    asm volatile("s_waitcnt vmcnt(0)" ::: "memory");
    __syncthreads();
    if (tid == 0) {
      __hip_atomic_store(FL + (size_t)(((dir << 9) | t) * 8 + bg) * 16 + rg, 1,
                         __ATOMIC_RELAXED, __HIP_MEMORY_SCOPE_AGENT);
    }
  }
}

// ---------------------------------------------------------------------------
// k3: EP[tb] += sum_j W2[j] * tanh( sum_k H[tb][k]*W1[j][N+k] + SP[b][j] )
//   same GEMM skeleton as k1, fused epilogue (u never materialized)
// ---------------------------------------------------------------------------
__global__ __launch_bounds__(256) void k3_attn(const float* __restrict__ Hm,
    const float* __restrict__ W1, const float* __restrict__ SP,
    const float* __restrict__ W2, float* __restrict__ EP) {
  __shared__ __align__(16) float As[8 * 128];
  __shared__ __align__(16) float Bs[8 * 256];
  __shared__ float esc[128 * 16];
  const int tid = threadIdx.x;
  const int m0 = blockIdx.x * 128;
  const int n0 = blockIdx.y * 256;
  const int mt = tid & 15;
  const int nt = tid >> 4;
  float acc[8][16];
#pragma unroll
  for (int i = 0; i < 8; ++i)
#pragma unroll
    for (int j = 0; j < 16; ++j) acc[i][j] = 0.f;
  const float* brow = W1 + (size_t)(n0 + tid) * (2 * Nn) + Nn;
  const int ai = tid >> 1;
  const int ak = (tid & 1) * 4;
  const float* arow = Hm + (size_t)(m0 + ai) * Nn + ak;
  for (int kt = 0; kt < 128; ++kt) {
    const int k0 = kt * 8;
    const float4 av = *(const float4*)(arow + k0);
    const float4 bv0 = *(const float4*)(brow + k0);
    const float4 bv1 = *(const float4*)(brow + k0 + 4);
    __syncthreads();
    As[(ak + 0) * 128 + ai] = av.x;
    As[(ak + 1) * 128 + ai] = av.y;
    As[(ak + 2) * 128 + ai] = av.z;
    As[(ak + 3) * 128 + ai] = av.w;
    Bs[0 * 256 + tid] = bv0.x;
    Bs[1 * 256 + tid] = bv0.y;
    Bs[2 * 256 + tid] = bv0.z;
    Bs[3 * 256 + tid] = bv0.w;
    Bs[4 * 256 + tid] = bv1.x;
    Bs[5 * 256 + tid] = bv1.y;
    Bs[6 * 256 + tid] = bv1.z;
    Bs[7 * 256 + tid] = bv1.w;
    __syncthreads();
#pragma unroll
    for (int k = 0; k < 8; ++k) {
      float a[8], bq[16];
      *(float4*)&a[0] = *(const float4*)&As[k * 128 + mt * 8];
      *(float4*)&a[4] = *(const float4*)&As[k * 128 + mt * 8 + 4];
      *(float4*)&bq[0] = *(const float4*)&Bs[k * 256 + nt * 16];
      *(float4*)&bq[4] = *(const float4*)&Bs[k * 256 + nt * 16 + 4];
      *(float4*)&bq[8] = *(const float4*)&Bs[k * 256 + nt * 16 + 8];
      *(float4*)&bq[12] = *(const float4*)&Bs[k * 256 + nt * 16 + 12];
#pragma unroll
      for (int mi = 0; mi < 8; ++mi)
#pragma unroll
        for (int ni = 0; ni < 16; ++ni) acc[mi][ni] += a[mi] * bq[ni];
    }
  }
  float w2v[16];
  *(float4*)&w2v[0] = *(const float4*)(W2 + n0 + nt * 16);
  *(float4*)&w2v[4] = *(const float4*)(W2 + n0 + nt * 16 + 4);
  *(float4*)&w2v[8] = *(const float4*)(W2 + n0 + nt * 16 + 8);
  *(float4*)&w2v[12] = *(const float4*)(W2 + n0 + nt * 16 + 12);
#pragma unroll
  for (int mi = 0; mi < 8; ++mi) {
    const int row = m0 + mt * 8 + mi;
    const int b = row & 63;
    const float* sp = SP + (size_t)b * Nn + n0 + nt * 16;
    float rp = 0.f;
#pragma unroll
    for (int ni = 0; ni < 16; ++ni) {
      const float u = tanhf(acc[mi][ni] + sp[ni]);
      rp += u * w2v[ni];
    }
    esc[(mt * 8 + mi) * 16 + nt] = rp;
  }
  __syncthreads();
  if (tid < 128) {
    float sum = 0.f;
#pragma unroll
    for (int qq = 0; qq < 16; ++qq) sum += esc[tid * 16 + qq];
    atomicAdd(EP + m0 + tid, sum);
  }
}

// ---------------------------------------------------------------------------
// k4: e = tanh(EP + b2); softmax over t (per b)
// ---------------------------------------------------------------------------
__global__ __launch_bounds__(256) void k4_softmax(const float* __restrict__ EP,
    const float* __restrict__ b2, float* __restrict__ AA) {
  const int b = blockIdx.x;
  const int tid = threadIdx.x;
  __shared__ float rbuf[256];
  const float b2v = b2[0];
  const float v0 = tanhf(EP[(size_t)tid * Bn + b] + b2v);
  const float v1 = tanhf(EP[(size_t)(tid + 256) * Bn + b] + b2v);
  rbuf[tid] = fmaxf(v0, v1);
  __syncthreads();
  for (int off = 128; off > 0; off >>= 1) {
    if (tid < off) rbuf[tid] = fmaxf(rbuf[tid], rbuf[tid + off]);
    __syncthreads();
  }
  const float M = rbuf[0];
  __syncthreads();
  const float e0 = expf(v0 - M);
  const float e1 = expf(v1 - M);
  rbuf[tid] = e0 + e1;
  __syncthreads();
  for (int off = 128; off > 0; off >>= 1) {
    if (tid < off) rbuf[tid] = rbuf[tid] + rbuf[tid + off];
    __syncthreads();
  }
  const float S = rbuf[0];
  AA[(size_t)tid * Bn + b] = e0 / S;
  AA[(size_t)(tid + 256) * Bn + b] = e1 / S;
}

// ---------------------------------------------------------------------------
// k5: out[b][n] = sum_t AA[t][b] * H[t][b][n]
// ---------------------------------------------------------------------------
__global__ __launch_bounds__(256) void k5_out(const float* __restrict__ AA,
    const float* __restrict__ Hm, float* __restrict__ out) {
  const int b = blockIdx.x;
  const int n = blockIdx.y * 256 + threadIdx.x;
  float o = 0.f;
#pragma unroll 8
  for (int t = 0; t < Tn; ++t)
    o += AA[(size_t)t * Bn + b] * Hm[(size_t)t * (Bn * Nn) + (size_t)b * Nn + n];
  out[(size_t)b * Nn + n] = o;
}

// ---------------------------------------------------------------------------
extern "C" void kernel_launch(void* const* d_in, const int* in_sizes, int n_in,
                              void* d_out, int out_size, void* d_ws, size_t ws_size,
                              hipStream_t stream) {
  const float* s     = (const float*)d_in[0];
  const float* x     = (const float*)d_in[1];
  const float* Wih_f = (const float*)d_in[2];
  const float* Whh_f = (const float*)d_in[3];
  const float* bih_f = (const float*)d_in[4];
  const float* bhh_f = (const float*)d_in[5];
  const float* Wih_b = (const float*)d_in[6];
  const float* Whh_b = (const float*)d_in[7];
  const float* bih_b = (const float*)d_in[8];
  const float* bhh_b = (const float*)d_in[9];
  const float* W1    = (const float*)d_in[10];
  const float* b1    = (const float*)d_in[11];
  const float* W2    = (const float*)d_in[12];
  const float* b2    = (const float*)d_in[13];
  float* out = (float*)d_out;

  float* XW = (float*)d_ws;                 // 33554432 f32 (134MB)
  float* Hm = XW + 33554432ULL;             // 33554432 f32 (134MB)
  float* SP = Hm + 33554432ULL;             // 65536 f32
  float* EP = SP + 65536ULL;                // 32768 f32
  float* AA = EP + 32768ULL;                // 32768 f32
  int* FL   = (int*)(AA + 32768ULL);        // 2*512*8*16 = 131072 ints (512KB)
  const size_t need =
      ((size_t)(33554432ULL * 2 + 65536 + 32768 + 32768)) * 4 + 131072ULL * 4;
  if (ws_size < need) return;  // workspace too small: fail visibly

  hipMemsetAsync(EP, 0, 32768 * sizeof(float), stream);
  hipMemsetAsync(FL, 0, 131072 * sizeof(int), stream);

  k0_sproj<<<dim3(64), 256, 0, stream>>>(s, W1, b1, SP);
  k1_gemm<<<dim3(256, 4), 256, 0, stream>>>(x, Wih_f, Wih_b, bih_f, bih_b, XW);
  k2_scan<<<dim3(256), 256, 0, stream>>>(XW, Whh_f, Whh_b, bhh_f, bhh_b, Hm, FL);
  k3_attn<<<dim3(256, 4), 256, 0, stream>>>(Hm, W1, SP, W2, EP);
  k4_softmax<<<dim3(64), 256, 0, stream>>>(EP, b2, AA);
  k5_out<<<dim3(64, 4), 256, 0, stream>>>(AA, Hm, out);
}

// Round 3
// 6284.671 us; speedup vs baseline: 2.5992x; 1.2728x over previous
//
#include <hip/hip_runtime.h>

#define Tn 512
#define Bn 64
#define Nn 1024
#define Hn 512

// ---------------------------------------------------------------------------
// k0: SP[b][j] = sum_i s[b][i] * W1[j][i]  + b1[j]    (first half of W1 rows)
// ---------------------------------------------------------------------------
__global__ __launch_bounds__(256) void k0_sproj(const float* __restrict__ s,
    const float* __restrict__ W1, const float* __restrict__ b1,
    float* __restrict__ SP) {
  const int b = blockIdx.x;
  const int tid = threadIdx.x;
  __shared__ float sl[Nn];
  for (int i = tid; i < Nn; i += 256) sl[i] = s[(size_t)b * Nn + i];
  __syncthreads();
#pragma unroll
  for (int qq = 0; qq < 4; ++qq) {
    const int j = qq * 256 + tid;
    const float* w = W1 + (size_t)j * (2 * Nn);
    float acc = 0.f;
    for (int i = 0; i < Nn; i += 4) {
      const float4 wv = *(const float4*)(w + i);
      acc += sl[i] * wv.x + sl[i + 1] * wv.y + sl[i + 2] * wv.z + sl[i + 3] * wv.w;
    }
    SP[(size_t)b * Nn + j] = acc + b1[j];
  }
}

// ---------------------------------------------------------------------------
// k1: XW[m][j] = sum_k X[m][k] * Wcat[j][k] + bias[j]
//   m = t*64+b (32768), j<512 -> Wih_f row j (+bih_f), j>=512 -> Wih_b (+bih_b)
//   BM=128 BN=256 BK=8, 256 threads, 8x16 micro-tile
// ---------------------------------------------------------------------------
__global__ __launch_bounds__(256) void k1_gemm(const float* __restrict__ X,
    const float* __restrict__ Wf, const float* __restrict__ Wb,
    const float* __restrict__ bif, const float* __restrict__ bib,
    float* __restrict__ XW) {
  __shared__ __align__(16) float As[8 * 128];
  __shared__ __align__(16) float Bs[8 * 256];
  const int tid = threadIdx.x;
  const int m0 = blockIdx.x * 128;
  const int n0 = blockIdx.y * 256;
  const int mt = tid & 15;
  const int nt = tid >> 4;
  float acc[8][16];
#pragma unroll
  for (int i = 0; i < 8; ++i)
#pragma unroll
    for (int j = 0; j < 16; ++j) acc[i][j] = 0.f;
  const int jg = n0 + tid;
  const float* brow = (jg < 512) ? (Wf + (size_t)jg * Nn) : (Wb + (size_t)(jg - 512) * Nn);
  const int ai = tid >> 1;
  const int ak = (tid & 1) * 4;
  const float* arow = X + (size_t)(m0 + ai) * Nn + ak;
  for (int kt = 0; kt < 128; ++kt) {
    const int k0 = kt * 8;
    const float4 av = *(const float4*)(arow + k0);
    const float4 bv0 = *(const float4*)(brow + k0);
    const float4 bv1 = *(const float4*)(brow + k0 + 4);
    __syncthreads();
    As[(ak + 0) * 128 + ai] = av.x;
    As[(ak + 1) * 128 + ai] = av.y;
    As[(ak + 2) * 128 + ai] = av.z;
    As[(ak + 3) * 128 + ai] = av.w;
    Bs[0 * 256 + tid] = bv0.x;
    Bs[1 * 256 + tid] = bv0.y;
    Bs[2 * 256 + tid] = bv0.z;
    Bs[3 * 256 + tid] = bv0.w;
    Bs[4 * 256 + tid] = bv1.x;
    Bs[5 * 256 + tid] = bv1.y;
    Bs[6 * 256 + tid] = bv1.z;
    Bs[7 * 256 + tid] = bv1.w;
    __syncthreads();
#pragma unroll
    for (int k = 0; k < 8; ++k) {
      float a[8], bq[16];
      *(float4*)&a[0] = *(const float4*)&As[k * 128 + mt * 8];
      *(float4*)&a[4] = *(const float4*)&As[k * 128 + mt * 8 + 4];
      *(float4*)&bq[0] = *(const float4*)&Bs[k * 256 + nt * 16];
      *(float4*)&bq[4] = *(const float4*)&Bs[k * 256 + nt * 16 + 4];
      *(float4*)&bq[8] = *(const float4*)&Bs[k * 256 + nt * 16 + 8];
      *(float4*)&bq[12] = *(const float4*)&Bs[k * 256 + nt * 16 + 12];
#pragma unroll
      for (int mi = 0; mi < 8; ++mi)
#pragma unroll
        for (int ni = 0; ni < 16; ++ni) acc[mi][ni] += a[mi] * bq[ni];
    }
  }
  float bias[16];
#pragma unroll
  for (int ni = 0; ni < 16; ++ni) {
    const int jc = n0 + nt * 16 + ni;
    bias[ni] = (jc < 512) ? bif[jc] : bib[jc - 512];
  }
#pragma unroll
  for (int mi = 0; mi < 8; ++mi) {
    float* orow = XW + (size_t)(m0 + mt * 8 + mi) * Nn + n0 + nt * 16;
#pragma unroll
    for (int c = 0; c < 4; ++c) {
      float4 v;
      v.x = acc[mi][c * 4 + 0] + bias[c * 4 + 0];
      v.y = acc[mi][c * 4 + 1] + bias[c * 4 + 1];
      v.z = acc[mi][c * 4 + 2] + bias[c * 4 + 2];
      v.w = acc[mi][c * 4 + 3] + bias[c * 4 + 3];
      *(float4*)(orow + c * 4) = v;
    }
  }
}

// ---------------------------------------------------------------------------
// k2: bidirectional RNN scan.  256 WGs = 2 dir x 8 bgroup x 16 rgroup.
//   Whh slice (32 rows x 512 k) transposed in LDS.  Per step:
//     consumer: 16-lane relaxed poll -> stage h[8 bb][512] into LDS via
//               device-scope (sc0 sc1) 8B atomic loads (read LLC directly,
//               NO acquire fence / NO buffer_inv -- R2's per-step L2
//               flash-invalidate storm was the 11.5us/step cost)
//     producer: write-through relaxed-agent h stores -> vmcnt(0) -> barrier
//               -> relaxed flag store
// ---------------------------------------------------------------------------
__global__ __launch_bounds__(256) void k2_scan(const float* __restrict__ XW,
    const float* __restrict__ Whh_f, const float* __restrict__ Whh_b,
    const float* __restrict__ bhh_f, const float* __restrict__ bhh_b,
    float* __restrict__ Hm, int* __restrict__ FL) {
  const int wg = blockIdx.x;
  const int dir = wg & 1;
  const int bg = (wg >> 1) & 7;
  const int rg = wg >> 4;  // 0..15
  const int tid = threadIdx.x;
  const int r = tid & 31;   // row within slice / stage column
  const int q = tid >> 5;   // k-slice 0..7 (64 k each) / stage batch row
  __shared__ float Wt[512 * 32];              // [k][r]  64KB
  __shared__ __align__(16) float Hs[8 * 512]; // [bb][k] 16KB staged h
  __shared__ float red[8 * 8 * 32];           // [q][bb][r] 8KB
  const float* Whh = dir ? Whh_b : Whh_f;
  const float* bhh = dir ? bhh_b : bhh_f;
  for (int idx = tid; idx < 32 * 128; idx += 256) {
    const int rl = idx & 31;
    const int k4 = idx >> 5;
    const float4 v = *(const float4*)(Whh + (size_t)(rg * 32 + rl) * Hn + k4 * 4);
    Wt[(k4 * 4 + 0) * 32 + rl] = v.x;
    Wt[(k4 * 4 + 1) * 32 + rl] = v.y;
    Wt[(k4 * 4 + 2) * 32 + rl] = v.z;
    Wt[(k4 * 4 + 3) * 32 + rl] = v.w;
  }
  const float bhh_r = bhh[rg * 32 + r];
  const int bb2 = tid >> 5;            // epilogue: 8 bb x 32 r
  const int bglob2 = bg * 8 + bb2;
  const int rglob = rg * 32 + r;
  const int coloff = dir * 512;
  const int k_lo = q * 64;
  for (int t = 0; t < Tn; ++t) {
    // issue this step's XW load before the flag wait (independent of h[t-1])
    const size_t xwrow = dir ? ((size_t)(Tn - 1 - t) * Bn + bglob2)
                             : ((size_t)t * Bn + bglob2);
    const float xwv = XW[xwrow * Nn + coloff + rglob];

    if (t > 0) {
      if (tid < 64) {  // wave 0: 16 flags polled in one coalesced load
        int* fp = FL + (size_t)(((dir << 9) | (t - 1)) * 8 + bg) * 16;
        while (true) {
          const int v = __hip_atomic_load(fp + (tid & 15), __ATOMIC_RELAXED,
                                          __HIP_MEMORY_SCOPE_AGENT);
          if (__all(v != 0)) break;
          __builtin_amdgcn_s_sleep(1);
        }
      }
      __syncthreads();
      // stage h_prev[8 bb][512] -> Hs via device-scope 8B loads (LLC-fresh)
      const int hprow = dir ? (Tn - t) : (t - 1);
      const unsigned long long* hrow64 =
          (const unsigned long long*)(Hm + (size_t)hprow * (Bn * Nn) +
                                      (size_t)(bg * 8 + q) * Nn + coloff);
      unsigned long long* hs64 = (unsigned long long*)Hs + q * 256;
#pragma unroll
      for (int u = 0; u < 8; ++u) {
        hs64[r + u * 32] = __hip_atomic_load(hrow64 + r + u * 32,
                                             __ATOMIC_RELAXED,
                                             __HIP_MEMORY_SCOPE_AGENT);
      }
      __syncthreads();
      float acc[8] = {0.f, 0.f, 0.f, 0.f, 0.f, 0.f, 0.f, 0.f};
      for (int k0 = k_lo; k0 < k_lo + 64; k0 += 4) {
        const float w0 = Wt[(k0 + 0) * 32 + r];
        const float w1 = Wt[(k0 + 1) * 32 + r];
        const float w2_ = Wt[(k0 + 2) * 32 + r];
        const float w3 = Wt[(k0 + 3) * 32 + r];
#pragma unroll
        for (int bb = 0; bb < 8; ++bb) {
          const float4 hv = *(const float4*)&Hs[bb * 512 + k0];  // broadcast
          acc[bb] += hv.x * w0 + hv.y * w1 + hv.z * w2_ + hv.w * w3;
        }
      }
#pragma unroll
      for (int bb = 0; bb < 8; ++bb) red[q * 256 + bb * 32 + r] = acc[bb];
    }
    __syncthreads();
    float ssum = 0.f;
    if (t > 0) {
#pragma unroll
      for (int qq = 0; qq < 8; ++qq) ssum += red[qq * 256 + bb2 * 32 + r];
    }
    const float pre = ssum + xwv + bhh_r;
    const float hv = tanhf(pre);
    const int hrow = dir ? (Tn - 1 - t) : t;
    // write-through (device-coherent) store: visible at LLC once vmcnt retires
    __hip_atomic_store(
        &Hm[(size_t)hrow * (Bn * Nn) + (size_t)bglob2 * Nn + coloff + rglob], hv,
        __ATOMIC_RELAXED, __HIP_MEMORY_SCOPE_AGENT);
    asm volatile("s_waitcnt vmcnt(0)" ::: "memory");
    __syncthreads();
    if (tid == 0) {
      __hip_atomic_store(FL + (size_t)(((dir << 9) | t) * 8 + bg) * 16 + rg, 1,
                         __ATOMIC_RELAXED, __HIP_MEMORY_SCOPE_AGENT);
    }
  }
}

// ---------------------------------------------------------------------------
// k3: EP[tb] += sum_j W2[j] * tanh( sum_k H[tb][k]*W1[j][N+k] + SP[b][j] )
//   same GEMM skeleton as k1, fused epilogue (u never materialized)
// ---------------------------------------------------------------------------
__global__ __launch_bounds__(256) void k3_attn(const float* __restrict__ Hm,
    const float* __restrict__ W1, const float* __restrict__ SP,
    const float* __restrict__ W2, float* __restrict__ EP) {
  __shared__ __align__(16) float As[8 * 128];
  __shared__ __align__(16) float Bs[8 * 256];
  __shared__ float esc[128 * 16];
  const int tid = threadIdx.x;
  const int m0 = blockIdx.x * 128;
  const int n0 = blockIdx.y * 256;
  const int mt = tid & 15;
  const int nt = tid >> 4;
  float acc[8][16];
#pragma unroll
  for (int i = 0; i < 8; ++i)
#pragma unroll
    for (int j = 0; j < 16; ++j) acc[i][j] = 0.f;
  const float* brow = W1 + (size_t)(n0 + tid) * (2 * Nn) + Nn;
  const int ai = tid >> 1;
  const int ak = (tid & 1) * 4;
  const float* arow = Hm + (size_t)(m0 + ai) * Nn + ak;
  for (int kt = 0; kt < 128; ++kt) {
    const int k0 = kt * 8;
    const float4 av = *(const float4*)(arow + k0);
    const float4 bv0 = *(const float4*)(brow + k0);
    const float4 bv1 = *(const float4*)(brow + k0 + 4);
    __syncthreads();
    As[(ak + 0) * 128 + ai] = av.x;
    As[(ak + 1) * 128 + ai] = av.y;
    As[(ak + 2) * 128 + ai] = av.z;
    As[(ak + 3) * 128 + ai] = av.w;
    Bs[0 * 256 + tid] = bv0.x;
    Bs[1 * 256 + tid] = bv0.y;
    Bs[2 * 256 + tid] = bv0.z;
    Bs[3 * 256 + tid] = bv0.w;
    Bs[4 * 256 + tid] = bv1.x;
    Bs[5 * 256 + tid] = bv1.y;
    Bs[6 * 256 + tid] = bv1.z;
    Bs[7 * 256 + tid] = bv1.w;
    __syncthreads();
#pragma unroll
    for (int k = 0; k < 8; ++k) {
      float a[8], bq[16];
      *(float4*)&a[0] = *(const float4*)&As[k * 128 + mt * 8];
      *(float4*)&a[4] = *(const float4*)&As[k * 128 + mt * 8 + 4];
      *(float4*)&bq[0] = *(const float4*)&Bs[k * 256 + nt * 16];
      *(float4*)&bq[4] = *(const float4*)&Bs[k * 256 + nt * 16 + 4];
      *(float4*)&bq[8] = *(const float4*)&Bs[k * 256 + nt * 16 + 8];
      *(float4*)&bq[12] = *(const float4*)&Bs[k * 256 + nt * 16 + 12];
#pragma unroll
      for (int mi = 0; mi < 8; ++mi)
#pragma unroll
        for (int ni = 0; ni < 16; ++ni) acc[mi][ni] += a[mi] * bq[ni];
    }
  }
  float w2v[16];
  *(float4*)&w2v[0] = *(const float4*)(W2 + n0 + nt * 16);
  *(float4*)&w2v[4] = *(const float4*)(W2 + n0 + nt * 16 + 4);
  *(float4*)&w2v[8] = *(const float4*)(W2 + n0 + nt * 16 + 8);
  *(float4*)&w2v[12] = *(const float4*)(W2 + n0 + nt * 16 + 12);
#pragma unroll
  for (int mi = 0; mi < 8; ++mi) {
    const int row = m0 + mt * 8 + mi;
    const int b = row & 63;
    const float* sp = SP + (size_t)b * Nn + n0 + nt * 16;
    float rp = 0.f;
#pragma unroll
    for (int ni = 0; ni < 16; ++ni) {
      const float u = tanhf(acc[mi][ni] + sp[ni]);
      rp += u * w2v[ni];
    }
    esc[(mt * 8 + mi) * 16 + nt] = rp;
  }
  __syncthreads();
  if (tid < 128) {
    float sum = 0.f;
#pragma unroll
    for (int qq = 0; qq < 16; ++qq) sum += esc[tid * 16 + qq];
    atomicAdd(EP + m0 + tid, sum);
  }
}

// ---------------------------------------------------------------------------
// k4: e = tanh(EP + b2); softmax over t (per b)
// ---------------------------------------------------------------------------
__global__ __launch_bounds__(256) void k4_softmax(const float* __restrict__ EP,
    const float* __restrict__ b2, float* __restrict__ AA) {
  const int b = blockIdx.x;
  const int tid = threadIdx.x;
  __shared__ float rbuf[256];
  const float b2v = b2[0];
  const float v0 = tanhf(EP[(size_t)tid * Bn + b] + b2v);
  const float v1 = tanhf(EP[(size_t)(tid + 256) * Bn + b] + b2v);
  rbuf[tid] = fmaxf(v0, v1);
  __syncthreads();
  for (int off = 128; off > 0; off >>= 1) {
    if (tid < off) rbuf[tid] = fmaxf(rbuf[tid], rbuf[tid + off]);
    __syncthreads();
  }
  const float M = rbuf[0];
  __syncthreads();
  const float e0 = expf(v0 - M);
  const float e1 = expf(v1 - M);
  rbuf[tid] = e0 + e1;
  __syncthreads();
  for (int off = 128; off > 0; off >>= 1) {
    if (tid < off) rbuf[tid] = rbuf[tid] + rbuf[tid + off];
    __syncthreads();
  }
  const float S = rbuf[0];
  AA[(size_t)tid * Bn + b] = e0 / S;
  AA[(size_t)(tid + 256) * Bn + b] = e1 / S;
}

// ---------------------------------------------------------------------------
// k5: out[b][n] = sum_t AA[t][b] * H[t][b][n]
// ---------------------------------------------------------------------------
__global__ __launch_bounds__(256) void k5_out(const float* __restrict__ AA,
    const float* __restrict__ Hm, float* __restrict__ out) {
  const int b = blockIdx.x;
  const int n = blockIdx.y * 256 + threadIdx.x;
  float o = 0.f;
#pragma unroll 8
  for (int t = 0; t < Tn; ++t)
    o += AA[(size_t)t * Bn + b] * Hm[(size_t)t * (Bn * Nn) + (size_t)b * Nn + n];
  out[(size_t)b * Nn + n] = o;
}

// ---------------------------------------------------------------------------
extern "C" void kernel_launch(void* const* d_in, const int* in_sizes, int n_in,
                              void* d_out, int out_size, void* d_ws, size_t ws_size,
                              hipStream_t stream) {
  const float* s     = (const float*)d_in[0];
  const float* x     = (const float*)d_in[1];
  const float* Wih_f = (const float*)d_in[2];
  const float* Whh_f = (const float*)d_in[3];
  const float* bih_f = (const float*)d_in[4];
  const float* bhh_f = (const float*)d_in[5];
  const float* Wih_b = (const float*)d_in[6];
  const float* Whh_b = (const float*)d_in[7];
  const float* bih_b = (const float*)d_in[8];
  const float* bhh_b = (const float*)d_in[9];
  const float* W1    = (const float*)d_in[10];
  const float* b1    = (const float*)d_in[11];
  const float* W2    = (const float*)d_in[12];
  const float* b2    = (const float*)d_in[13];
  float* out = (float*)d_out;

  float* XW = (float*)d_ws;                 // 33554432 f32 (134MB)
  float* Hm = XW + 33554432ULL;             // 33554432 f32 (134MB)
  float* SP = Hm + 33554432ULL;             // 65536 f32
  float* EP = SP + 65536ULL;                // 32768 f32
  float* AA = EP + 32768ULL;                // 32768 f32
  int* FL   = (int*)(AA + 32768ULL);        // 2*512*8*16 = 131072 ints (512KB)
  const size_t need =
      ((size_t)(33554432ULL * 2 + 65536 + 32768 + 32768)) * 4 + 131072ULL * 4;
  if (ws_size < need) return;  // workspace too small: fail visibly

  hipMemsetAsync(EP, 0, 32768 * sizeof(float), stream);
  hipMemsetAsync(FL, 0, 131072 * sizeof(int), stream);

  k0_sproj<<<dim3(64), 256, 0, stream>>>(s, W1, b1, SP);
  k1_gemm<<<dim3(256, 4), 256, 0, stream>>>(x, Wih_f, Wih_b, bih_f, bih_b, XW);
  k2_scan<<<dim3(256), 256, 0, stream>>>(XW, Whh_f, Whh_b, bhh_f, bhh_b, Hm, FL);
  k3_attn<<<dim3(256, 4), 256, 0, stream>>>(Hm, W1, SP, W2, EP);
  k4_softmax<<<dim3(64), 256, 0, stream>>>(EP, b2, AA);
  k5_out<<<dim3(64, 4), 256, 0, stream>>>(AA, Hm, out);
}

// Round 4
// 4831.947 us; speedup vs baseline: 3.3807x; 1.3006x over previous
//
#include <hip/hip_runtime.h>

#define Tn 512
#define Bn 64
#define Nn 1024
#define Hn 512

typedef __attribute__((ext_vector_type(8))) short short8;
typedef __attribute__((ext_vector_type(4))) float f32x4;

__device__ __forceinline__ unsigned short f2bf_hi(float x) {
  unsigned u = __builtin_bit_cast(unsigned, x);
  unsigned r = u + 0x7FFFu + ((u >> 16) & 1u);  // RNE
  return (unsigned short)(r >> 16);
}
__device__ __forceinline__ float bf2f(unsigned short b) {
  unsigned u = ((unsigned)b) << 16;
  return __builtin_bit_cast(float, u);
}

// ---------------------------------------------------------------------------
// k0: SP[b][j] = sum_i s[b][i] * W1[j][i]  + b1[j]    (first half of W1 rows)
// ---------------------------------------------------------------------------
__global__ __launch_bounds__(256) void k0_sproj(const float* __restrict__ s,
    const float* __restrict__ W1, const float* __restrict__ b1,
    float* __restrict__ SP) {
  const int b = blockIdx.x;
  const int tid = threadIdx.x;
  __shared__ float sl[Nn];
  for (int i = tid; i < Nn; i += 256) sl[i] = s[(size_t)b * Nn + i];
  __syncthreads();
#pragma unroll
  for (int qq = 0; qq < 4; ++qq) {
    const int j = qq * 256 + tid;
    const float* w = W1 + (size_t)j * (2 * Nn);
    float acc = 0.f;
    for (int i = 0; i < Nn; i += 4) {
      const float4 wv = *(const float4*)(w + i);
      acc += sl[i] * wv.x + sl[i + 1] * wv.y + sl[i + 2] * wv.z + sl[i + 3] * wv.w;
    }
    SP[(size_t)b * Nn + j] = acc + b1[j];
  }
}

// ---------------------------------------------------------------------------
// k1_mfma: XW[m][j] = sum_k X[m][k]*Wcat[j][k] + bias[j]  via bf16 3-split MFMA
//   128x128 tile, BK=32, 4 waves (64x64 quadrant each), 16x16x32 bf16 MFMA.
//   hi/lo split: X=Xh+Xl, W=Wh+Wl; D = Xh*Wh + Xh*Wl + Xl*Wh (lo*lo ~2^-18, dropped)
//   LDS rows padded to 40 ushorts (80B) -> even bank-quad spread on b128 reads.
// ---------------------------------------------------------------------------
#define LDA 40
__global__ __launch_bounds__(256) void k1_mfma(const float* __restrict__ X,
    const float* __restrict__ Wf, const float* __restrict__ Wb,
    const float* __restrict__ bif, const float* __restrict__ bib,
    float* __restrict__ XW) {
  __shared__ __align__(16) unsigned short Ahi[128 * LDA];
  __shared__ __align__(16) unsigned short Alo[128 * LDA];
  __shared__ __align__(16) unsigned short Bhi[128 * LDA];
  __shared__ __align__(16) unsigned short Blo[128 * LDA];
  const int tid = threadIdx.x;
  const int n0 = blockIdx.x * 128;
  const int m0 = blockIdx.y * 128;
  const int lane = tid & 63;
  const int w = tid >> 6;
  const int mw = (w >> 1) * 64, nw = (w & 1) * 64;
  const int l15 = lane & 15, l4 = lane >> 4;

  const float* bsrc;
  const float* bias_base;
  if (n0 < 512) { bsrc = Wf + (size_t)n0 * Nn; bias_base = bif + n0; }
  else          { bsrc = Wb + (size_t)(n0 - 512) * Nn; bias_base = bib + (n0 - 512); }

  const int srow = tid >> 1, scol = (tid & 1) * 16;
  const float* ag = X + (size_t)(m0 + srow) * Nn + scol;
  const float* bg = bsrc + (size_t)srow * Nn + scol;

  f32x4 acc[4][4];
#pragma unroll
  for (int i = 0; i < 4; ++i)
#pragma unroll
    for (int j = 0; j < 4; ++j) acc[i][j] = (f32x4){0.f, 0.f, 0.f, 0.f};

  for (int kt = 0; kt < 32; ++kt) {
    const int k0 = kt * 32;
    float4 av[4], bv[4];
#pragma unroll
    for (int c = 0; c < 4; ++c) {
      av[c] = *(const float4*)(ag + k0 + c * 4);
      bv[c] = *(const float4*)(bg + k0 + c * 4);
    }
    __syncthreads();
#pragma unroll
    for (int c = 0; c < 4; ++c) {
      const float a4[4] = {av[c].x, av[c].y, av[c].z, av[c].w};
      const float b4[4] = {bv[c].x, bv[c].y, bv[c].z, bv[c].w};
      ushort4 ah, al, bh, bl;
      unsigned short* ahp = (unsigned short*)&ah;
      unsigned short* alp = (unsigned short*)&al;
      unsigned short* bhp = (unsigned short*)&bh;
      unsigned short* blp = (unsigned short*)&bl;
#pragma unroll
      for (int e = 0; e < 4; ++e) {
        const unsigned short h = f2bf_hi(a4[e]);
        ahp[e] = h; alp[e] = f2bf_hi(a4[e] - bf2f(h));
        const unsigned short g = f2bf_hi(b4[e]);
        bhp[e] = g; blp[e] = f2bf_hi(b4[e] - bf2f(g));
      }
      const int off = srow * LDA + scol + c * 4;
      *(ushort4*)&Ahi[off] = ah; *(ushort4*)&Alo[off] = al;
      *(ushort4*)&Bhi[off] = bh; *(ushort4*)&Blo[off] = bl;
    }
    __syncthreads();
    short8 afh[4], afl[4];
#pragma unroll
    for (int mi = 0; mi < 4; ++mi) {
      const int off = (mw + mi * 16 + l15) * LDA + l4 * 8;
      afh[mi] = *(const short8*)&Ahi[off];
      afl[mi] = *(const short8*)&Alo[off];
    }
#pragma unroll
    for (int ni = 0; ni < 4; ++ni) {
      const int off = (nw + ni * 16 + l15) * LDA + l4 * 8;
      const short8 bfh = *(const short8*)&Bhi[off];
      const short8 bfl = *(const short8*)&Blo[off];
#pragma unroll
      for (int mi = 0; mi < 4; ++mi) {
        acc[mi][ni] = __builtin_amdgcn_mfma_f32_16x16x32_bf16(afh[mi], bfh, acc[mi][ni], 0, 0, 0);
        acc[mi][ni] = __builtin_amdgcn_mfma_f32_16x16x32_bf16(afh[mi], bfl, acc[mi][ni], 0, 0, 0);
        acc[mi][ni] = __builtin_amdgcn_mfma_f32_16x16x32_bf16(afl[mi], bfh, acc[mi][ni], 0, 0, 0);
      }
    }
  }
  // epilogue: + bias, store f32.  C/D map: col=lane&15, row=(lane>>4)*4+reg
#pragma unroll
  for (int ni = 0; ni < 4; ++ni) {
    const int col = n0 + nw + ni * 16 + l15;
    const float bias = bias_base[nw + ni * 16 + l15];
#pragma unroll
    for (int mi = 0; mi < 4; ++mi) {
      const int row = m0 + mw + mi * 16 + l4 * 4;
#pragma unroll
      for (int reg = 0; reg < 4; ++reg)
        XW[(size_t)(row + reg) * Nn + col] = acc[mi][ni][reg] + bias;
    }
  }
}

// ---------------------------------------------------------------------------
// k2: bidirectional RNN scan (UNCHANGED from R3 -- verified protocol).
// ---------------------------------------------------------------------------
__global__ __launch_bounds__(256) void k2_scan(const float* __restrict__ XW,
    const float* __restrict__ Whh_f, const float* __restrict__ Whh_b,
    const float* __restrict__ bhh_f, const float* __restrict__ bhh_b,
    float* __restrict__ Hm, int* __restrict__ FL) {
  const int wg = blockIdx.x;
  const int dir = wg & 1;
  const int bg = (wg >> 1) & 7;
  const int rg = wg >> 4;  // 0..15
  const int tid = threadIdx.x;
  const int r = tid & 31;
  const int q = tid >> 5;
  __shared__ float Wt[512 * 32];
  __shared__ __align__(16) float Hs[8 * 512];
  __shared__ float red[8 * 8 * 32];
  const float* Whh = dir ? Whh_b : Whh_f;
  const float* bhh = dir ? bhh_b : bhh_f;
  for (int idx = tid; idx < 32 * 128; idx += 256) {
    const int rl = idx & 31;
    const int k4 = idx >> 5;
    const float4 v = *(const float4*)(Whh + (size_t)(rg * 32 + rl) * Hn + k4 * 4);
    Wt[(k4 * 4 + 0) * 32 + rl] = v.x;
    Wt[(k4 * 4 + 1) * 32 + rl] = v.y;
    Wt[(k4 * 4 + 2) * 32 + rl] = v.z;
    Wt[(k4 * 4 + 3) * 32 + rl] = v.w;
  }
  const float bhh_r = bhh[rg * 32 + r];
  const int bb2 = tid >> 5;
  const int bglob2 = bg * 8 + bb2;
  const int rglob = rg * 32 + r;
  const int coloff = dir * 512;
  const int k_lo = q * 64;
  for (int t = 0; t < Tn; ++t) {
    const size_t xwrow = dir ? ((size_t)(Tn - 1 - t) * Bn + bglob2)
                             : ((size_t)t * Bn + bglob2);
    const float xwv = XW[xwrow * Nn + coloff + rglob];

    if (t > 0) {
      if (tid < 64) {
        int* fp = FL + (size_t)(((dir << 9) | (t - 1)) * 8 + bg) * 16;
        while (true) {
          const int v = __hip_atomic_load(fp + (tid & 15), __ATOMIC_RELAXED,
                                          __HIP_MEMORY_SCOPE_AGENT);
          if (__all(v != 0)) break;
          __builtin_amdgcn_s_sleep(1);
        }
      }
      __syncthreads();
      const int hprow = dir ? (Tn - t) : (t - 1);
      const unsigned long long* hrow64 =
          (const unsigned long long*)(Hm + (size_t)hprow * (Bn * Nn) +
                                      (size_t)(bg * 8 + q) * Nn + coloff);
      unsigned long long* hs64 = (unsigned long long*)Hs + q * 256;
#pragma unroll
      for (int u = 0; u < 8; ++u) {
        hs64[r + u * 32] = __hip_atomic_load(hrow64 + r + u * 32,
                                             __ATOMIC_RELAXED,
                                             __HIP_MEMORY_SCOPE_AGENT);
      }
      __syncthreads();
      float acc[8] = {0.f, 0.f, 0.f, 0.f, 0.f, 0.f, 0.f, 0.f};
      for (int k0 = k_lo; k0 < k_lo + 64; k0 += 4) {
        const float w0 = Wt[(k0 + 0) * 32 + r];
        const float w1 = Wt[(k0 + 1) * 32 + r];
        const float w2_ = Wt[(k0 + 2) * 32 + r];
        const float w3 = Wt[(k0 + 3) * 32 + r];
#pragma unroll
        for (int bb = 0; bb < 8; ++bb) {
          const float4 hv = *(const float4*)&Hs[bb * 512 + k0];
          acc[bb] += hv.x * w0 + hv.y * w1 + hv.z * w2_ + hv.w * w3;
        }
      }
#pragma unroll
      for (int bb = 0; bb < 8; ++bb) red[q * 256 + bb * 32 + r] = acc[bb];
    }
    __syncthreads();
    float ssum = 0.f;
    if (t > 0) {
#pragma unroll
      for (int qq = 0; qq < 8; ++qq) ssum += red[qq * 256 + bb2 * 32 + r];
    }
    const float pre = ssum + xwv + bhh_r;
    const float hv = tanhf(pre);
    const int hrow = dir ? (Tn - 1 - t) : t;
    __hip_atomic_store(
        &Hm[(size_t)hrow * (Bn * Nn) + (size_t)bglob2 * Nn + coloff + rglob], hv,
        __ATOMIC_RELAXED, __HIP_MEMORY_SCOPE_AGENT);
    asm volatile("s_waitcnt vmcnt(0)" ::: "memory");
    __syncthreads();
    if (tid == 0) {
      __hip_atomic_store(FL + (size_t)(((dir << 9) | t) * 8 + bg) * 16 + rg, 1,
                         __ATOMIC_RELAXED, __HIP_MEMORY_SCOPE_AGENT);
    }
  }
}

// ---------------------------------------------------------------------------
// k3_mfma: EP[m] += sum_j W2[j]*tanh(sum_k H[m][k]*W1[j][N+k] + SP[b][j])
//   same MFMA skeleton as k1; epilogue: +SP (LDS-staged), tanh, *W2,
//   row-reduce over the 16-lane col group via shfl_xor, atomicAdd into EP.
// ---------------------------------------------------------------------------
__global__ __launch_bounds__(256) void k3_mfma(const float* __restrict__ Hm,
    const float* __restrict__ W1, const float* __restrict__ SP,
    const float* __restrict__ W2, float* __restrict__ EP) {
  __shared__ __align__(16) unsigned short Ahi[128 * LDA];
  __shared__ __align__(16) unsigned short Alo[128 * LDA];
  __shared__ __align__(16) unsigned short Bhi[128 * LDA];
  __shared__ __align__(16) unsigned short Blo[128 * LDA];
  __shared__ __align__(16) float SPs[64 * 128];
  const int tid = threadIdx.x;
  const int n0 = blockIdx.x * 128;
  const int m0 = blockIdx.y * 128;
  const int lane = tid & 63;
  const int w = tid >> 6;
  const int mw = (w >> 1) * 64, nw = (w & 1) * 64;
  const int l15 = lane & 15, l4 = lane >> 4;

  // stage SP slice: SPs[b64][c] = SP[b64][n0+c]  (b64 = row&63 since m0%128==0)
  {
    const int r64 = tid >> 2, c0 = (tid & 3) * 32;
    const float* sps = SP + (size_t)r64 * Nn + n0 + c0;
    float* spd = &SPs[r64 * 128 + c0];
#pragma unroll
    for (int c = 0; c < 8; ++c) *(float4*)(spd + c * 4) = *(const float4*)(sps + c * 4);
  }

  const int srow = tid >> 1, scol = (tid & 1) * 16;
  const float* ag = Hm + (size_t)(m0 + srow) * Nn + scol;
  const float* bg = W1 + (size_t)(n0 + srow) * (2 * Nn) + Nn + scol;

  f32x4 acc[4][4];
#pragma unroll
  for (int i = 0; i < 4; ++i)
#pragma unroll
    for (int j = 0; j < 4; ++j) acc[i][j] = (f32x4){0.f, 0.f, 0.f, 0.f};

  for (int kt = 0; kt < 32; ++kt) {
    const int k0 = kt * 32;
    float4 av[4], bv[4];
#pragma unroll
    for (int c = 0; c < 4; ++c) {
      av[c] = *(const float4*)(ag + k0 + c * 4);
      bv[c] = *(const float4*)(bg + k0 + c * 4);
    }
    __syncthreads();
#pragma unroll
    for (int c = 0; c < 4; ++c) {
      const float a4[4] = {av[c].x, av[c].y, av[c].z, av[c].w};
      const float b4[4] = {bv[c].x, bv[c].y, bv[c].z, bv[c].w};
      ushort4 ah, al, bh, bl;
      unsigned short* ahp = (unsigned short*)&ah;
      unsigned short* alp = (unsigned short*)&al;
      unsigned short* bhp = (unsigned short*)&bh;
      unsigned short* blp = (unsigned short*)&bl;
#pragma unroll
      for (int e = 0; e < 4; ++e) {
        const unsigned short h = f2bf_hi(a4[e]);
        ahp[e] = h; alp[e] = f2bf_hi(a4[e] - bf2f(h));
        const unsigned short g = f2bf_hi(b4[e]);
        bhp[e] = g; blp[e] = f2bf_hi(b4[e] - bf2f(g));
      }
      const int off = srow * LDA + scol + c * 4;
      *(ushort4*)&Ahi[off] = ah; *(ushort4*)&Alo[off] = al;
      *(ushort4*)&Bhi[off] = bh; *(ushort4*)&Blo[off] = bl;
    }
    __syncthreads();
    short8 afh[4], afl[4];
#pragma unroll
    for (int mi = 0; mi < 4; ++mi) {
      const int off = (mw + mi * 16 + l15) * LDA + l4 * 8;
      afh[mi] = *(const short8*)&Ahi[off];
      afl[mi] = *(const short8*)&Alo[off];
    }
#pragma unroll
    for (int ni = 0; ni < 4; ++ni) {
      const int off = (nw + ni * 16 + l15) * LDA + l4 * 8;
      const short8 bfh = *(const short8*)&Bhi[off];
      const short8 bfl = *(const short8*)&Blo[off];
#pragma unroll
      for (int mi = 0; mi < 4; ++mi) {
        acc[mi][ni] = __builtin_amdgcn_mfma_f32_16x16x32_bf16(afh[mi], bfh, acc[mi][ni], 0, 0, 0);
        acc[mi][ni] = __builtin_amdgcn_mfma_f32_16x16x32_bf16(afh[mi], bfl, acc[mi][ni], 0, 0, 0);
        acc[mi][ni] = __builtin_amdgcn_mfma_f32_16x16x32_bf16(afl[mi], bfh, acc[mi][ni], 0, 0, 0);
      }
    }
  }
  // epilogue
  float rs[4][4];
#pragma unroll
  for (int mi = 0; mi < 4; ++mi)
#pragma unroll
    for (int reg = 0; reg < 4; ++reg) rs[mi][reg] = 0.f;
#pragma unroll
  for (int ni = 0; ni < 4; ++ni) {
    const int col_l = nw + ni * 16 + l15;
    const float w2v = W2[n0 + col_l];
#pragma unroll
    for (int mi = 0; mi < 4; ++mi) {
      const int rl = mw + mi * 16 + l4 * 4;
#pragma unroll
      for (int reg = 0; reg < 4; ++reg) {
        const int b64 = (rl + reg) & 63;
        const float u = tanhf(acc[mi][ni][reg] + SPs[b64 * 128 + col_l]);
        rs[mi][reg] += u * w2v;
      }
    }
  }
#pragma unroll
  for (int mi = 0; mi < 4; ++mi)
#pragma unroll
    for (int reg = 0; reg < 4; ++reg) {
      float v = rs[mi][reg];
#pragma unroll
      for (int msk = 1; msk < 16; msk <<= 1) v += __shfl_xor(v, msk);
      if (l15 == 0)
        atomicAdd(EP + m0 + mw + mi * 16 + l4 * 4 + reg, v);
    }
}

// ---------------------------------------------------------------------------
// k4: e = tanh(EP + b2); softmax over t (per b)
// ---------------------------------------------------------------------------
__global__ __launch_bounds__(256) void k4_softmax(const float* __restrict__ EP,
    const float* __restrict__ b2, float* __restrict__ AA) {
  const int b = blockIdx.x;
  const int tid = threadIdx.x;
  __shared__ float rbuf[256];
  const float b2v = b2[0];
  const float v0 = tanhf(EP[(size_t)tid * Bn + b] + b2v);
  const float v1 = tanhf(EP[(size_t)(tid + 256) * Bn + b] + b2v);
  rbuf[tid] = fmaxf(v0, v1);
  __syncthreads();
  for (int off = 128; off > 0; off >>= 1) {
    if (tid < off) rbuf[tid] = fmaxf(rbuf[tid], rbuf[tid + off]);
    __syncthreads();
  }
  const float M = rbuf[0];
  __syncthreads();
  const float e0 = expf(v0 - M);
  const float e1 = expf(v1 - M);
  rbuf[tid] = e0 + e1;
  __syncthreads();
  for (int off = 128; off > 0; off >>= 1) {
    if (tid < off) rbuf[tid] = rbuf[tid] + rbuf[tid + off];
    __syncthreads();
  }
  const float S = rbuf[0];
  AA[(size_t)tid * Bn + b] = e0 / S;
  AA[(size_t)(tid + 256) * Bn + b] = e1 / S;
}

// ---------------------------------------------------------------------------
// k5: out[b][n] = sum_t AA[t][b] * H[t][b][n]
// ---------------------------------------------------------------------------
__global__ __launch_bounds__(256) void k5_out(const float* __restrict__ AA,
    const float* __restrict__ Hm, float* __restrict__ out) {
  const int b = blockIdx.x;
  const int n = blockIdx.y * 256 + threadIdx.x;
  float o = 0.f;
#pragma unroll 8
  for (int t = 0; t < Tn; ++t)
    o += AA[(size_t)t * Bn + b] * Hm[(size_t)t * (Bn * Nn) + (size_t)b * Nn + n];
  out[(size_t)b * Nn + n] = o;
}

// ---------------------------------------------------------------------------
extern "C" void kernel_launch(void* const* d_in, const int* in_sizes, int n_in,
                              void* d_out, int out_size, void* d_ws, size_t ws_size,
                              hipStream_t stream) {
  const float* s     = (const float*)d_in[0];
  const float* x     = (const float*)d_in[1];
  const float* Wih_f = (const float*)d_in[2];
  const float* Whh_f = (const float*)d_in[3];
  const float* bih_f = (const float*)d_in[4];
  const float* bhh_f = (const float*)d_in[5];
  const float* Wih_b = (const float*)d_in[6];
  const float* Whh_b = (const float*)d_in[7];
  const float* bih_b = (const float*)d_in[8];
  const float* bhh_b = (const float*)d_in[9];
  const float* W1    = (const float*)d_in[10];
  const float* b1    = (const float*)d_in[11];
  const float* W2    = (const float*)d_in[12];
  const float* b2    = (const float*)d_in[13];
  float* out = (float*)d_out;

  float* XW = (float*)d_ws;                 // 33554432 f32 (134MB)
  float* Hm = XW + 33554432ULL;             // 33554432 f32 (134MB)
  float* SP = Hm + 33554432ULL;             // 65536 f32
  float* EP = SP + 65536ULL;                // 32768 f32
  float* AA = EP + 32768ULL;                // 32768 f32
  int* FL   = (int*)(AA + 32768ULL);        // 2*512*8*16 = 131072 ints (512KB)
  const size_t need =
      ((size_t)(33554432ULL * 2 + 65536 + 32768 + 32768)) * 4 + 131072ULL * 4;
  if (ws_size < need) return;  // workspace too small: fail visibly

  hipMemsetAsync(EP, 0, 32768 * sizeof(float), stream);
  hipMemsetAsync(FL, 0, 131072 * sizeof(int), stream);

  k0_sproj<<<dim3(64), 256, 0, stream>>>(s, W1, b1, SP);
  k1_mfma<<<dim3(8, 256), 256, 0, stream>>>(x, Wih_f, Wih_b, bih_f, bih_b, XW);
  k2_scan<<<dim3(256), 256, 0, stream>>>(XW, Whh_f, Whh_b, bhh_f, bhh_b, Hm, FL);
  k3_mfma<<<dim3(8, 256), 256, 0, stream>>>(Hm, W1, SP, W2, EP);
  k4_softmax<<<dim3(64), 256, 0, stream>>>(EP, b2, AA);
  k5_out<<<dim3(64, 4), 256, 0, stream>>>(AA, Hm, out);
}